// Round 8
// baseline (243.879 us; speedup 1.0000x reference)
//
#include <hip/hip_runtime.h>

#define EPS_C 0.05f
#define BLOCK 512     /* 8 waves */
#define BPB   16384   /* elems per block: 8 waves x 2 units x 1024 */

typedef int i4 __attribute__((ext_vector_type(4)));
typedef float f4 __attribute__((ext_vector_type(4)));
typedef unsigned int u2 __attribute__((ext_vector_type(2)));

// Build the 6-entry change table into LDS (thread 0 only; caller syncs).
__device__ __forceinline__ void build_table(const float* bd_p, const float* d_p,
                                            const float* s_p, const float* inc_p,
                                            const float* bi_p, float* cs) {
  if (threadIdx.x == 0) {
    float bd = *bd_p, d = *d_p, s = *s_p, inc = *inc_p, bi = *bi_p;
    cs[0] = 0.0f;                                   // cat 0 (unused)
    cs[1] = fminf(bd, fminf(0.0f, d)) - EPS_C;      // big decrease
    cs[2] = fminf(fmaxf(d, bd + EPS_C), -EPS_C);    // decrease (clip)
    cs[3] = s;                                      // same
    cs[4] = fminf(fmaxf(inc, EPS_C), bi - EPS_C);   // increase (clip)
    cs[5] = fmaxf(bi, fmaxf(0.0f, inc) + EPS_C);    // big increase
    cs[6] = 0.0f; cs[7] = 0.0f;
  }
}

// K1: block b owns 16384 elems (8 waves x 2 units x 1024). Per unit, lane l
// packs rounds r=0..3 (elems ubase + r*256 + 4l) into one uint2 -> ONE
// coalesced 8B store per unit (512B/wave). Emits per-unit fine sums and the
// block sum coarse[b]. Input loads NT (read-once); pack stores cached (K2
// re-reads from the same XCD's L2: same blockIdx -> same XCD both launches).
__global__ __launch_bounds__(BLOCK) void k_pack_reduce(
    const int* __restrict__ ann, const float* bd, const float* d,
    const float* s, const float* inc, const float* bi,
    u2* __restrict__ pack, float* __restrict__ coarse,
    float* __restrict__ fine) {
  __shared__ float cs[8];
  __shared__ float wsum[8];
  build_table(bd, d, s, inc, bi, cs);
  __syncthreads();
  const int t = threadIdx.x, lane = t & 63, w = t >> 6, b = blockIdx.x;
  const size_t ebase = (size_t)b * BPB + (size_t)w * 2048;  // wave's first elem
  const i4* in4 = (const i4*)ann + (ebase >> 2) + lane;
  float fs[2];
#pragma unroll
  for (int u = 0; u < 2; ++u) {
    unsigned lo = 0, hi = 0;
    float sum = 0.0f;
#pragma unroll
    for (int r = 0; r < 4; ++r) {
      i4 v = __builtin_nontemporal_load(&in4[u * 256 + r * 64]);
      sum += cs[v.x] + cs[v.y] + cs[v.z] + cs[v.w];
      unsigned nib = (unsigned)v.x | ((unsigned)v.y << 4) |
                     ((unsigned)v.z << 8) | ((unsigned)v.w << 12);
      if (r & 1) { if (r < 2) lo |= nib << 16; else hi |= nib << 16; }
      else       { if (r < 2) lo |= nib;       else hi |= nib; }
    }
    pack[((size_t)b * 16 + w * 2 + u) * 64 + lane] = (u2){lo, hi};
#pragma unroll
    for (int off = 32; off >= 1; off >>= 1) sum += __shfl_xor(sum, off, 64);
    fs[u] = sum;
  }
  if (lane == 0) {
    fine[b * 16 + w * 2 + 0] = fs[0];
    fine[b * 16 + w * 2 + 1] = fs[1];
    wsum[w] = fs[0] + fs[1];
  }
  __syncthreads();
  if (t == 0) {
    float tot = 0.0f;
#pragma unroll
    for (int i = 0; i < 8; ++i) tot += wsum[i];
    coarse[b] = tot;
  }
}

// K2: block b owns the same 16384 elems. All independent loads (pack uint2s,
// fine, origin) issue before the coarse-prefix loop (<=4 L2-hot iters) so
// their latency hides under it. One __syncthreads total; tail barrier-free.
__global__ __launch_bounds__(BLOCK) void k_scan_out(
    const u2* __restrict__ pack, const float* __restrict__ coarse,
    const float* __restrict__ fine, const float* __restrict__ origin,
    const float* bd, const float* d, const float* s, const float* inc,
    const float* bi, float* __restrict__ out, int nb) {
  __shared__ float cs[8];
  __shared__ float ws2[8];
  build_table(bd, d, s, inc, bi, cs);
  const int t = threadIdx.x, lane = t & 63, w = t >> 6, b = blockIdx.x;

  // prefetch everything independent of the coarse loop
  const u2 pk0 = pack[((size_t)b * 16 + w * 2 + 0) * 64 + lane];
  const u2 pk1 = pack[((size_t)b * 16 + w * 2 + 1) * 64 + lane];
  float f = (lane < 16) ? fine[b * 16 + lane] : 0.0f;
  const float org = *origin;

  // block-exclusive prefix over coarse[0..b): <=4 coalesced iters
  float p = 0.0f;
  for (int i = t; i < b; i += BLOCK) p += coarse[i];
#pragma unroll
  for (int off = 32; off >= 1; off >>= 1) p += __shfl_xor(p, off, 64);
  if (lane == 0) ws2[w] = p;

  // in-block unit offsets: inclusive 16-lane shfl scan of fine (no LDS dep)
#pragma unroll
  for (int off = 1; off < 16; off <<= 1) {
    float y = __shfl_up(f, off, 64);
    if (lane >= off && lane < 16) f += y;
  }

  __syncthreads();                       // covers cs[] and ws2[]
  float P = org;
#pragma unroll
  for (int i = 0; i < 8; ++i) P += ws2[i];

  if (b == nb - 1 && w == 0 && lane == 15)
    out[(size_t)nb * BPB] = P + f;       // out[N] = origin + grand total

  const u2 pks[2] = {pk0, pk1};
#pragma unroll
  for (int h = 0; h < 2; ++h) {
    const int j = w * 2 + h;             // unit index within block (0..15)
    float carry = P + ((j > 0) ? __shfl(f, j - 1, 64) : 0.0f);
    const u2 pk = pks[h];
    const size_t ubase = (size_t)b * BPB + (size_t)j * 1024;
#pragma unroll
    for (int r = 0; r < 4; ++r) {
      const unsigned pw = (r < 2) ? pk.x : pk.y;
      const unsigned us = (r & 1) ? (pw >> 16) : (pw & 0xFFFFu);
      const float v0 = cs[us & 0xFu];
      const float v1 = cs[(us >> 4) & 0xFu];
      const float v2 = cs[(us >> 8) & 0xFu];
      const float v3 = cs[(us >> 12) & 0xFu];
      const float s4 = v0 + v1 + v2 + v3;
      float x = s4;                      // inclusive wave scan of 4-elem sums
#pragma unroll
      for (int off = 1; off < 64; off <<= 1) {
        float y = __shfl_up(x, off, 64);
        if (lane >= off) x += y;
      }
      const float off0 = carry + (x - s4);
      f4 o;
      o.x = off0;
      o.y = off0 + v0;
      o.z = o.y + v1;
      o.w = o.z + v2;
      __builtin_nontemporal_store(o, (f4*)(out + ubase + r * 256 + lane * 4));
      carry += __shfl(x, 63, 64);        // round total -> next round
    }
  }
}

extern "C" void kernel_launch(void* const* d_in, const int* in_sizes, int n_in,
                              void* d_out, int out_size, void* d_ws, size_t ws_size,
                              hipStream_t stream) {
  const int*   ann    = (const int*)d_in[0];
  const float* origin = (const float*)d_in[1];
  const float* bd     = (const float*)d_in[2];
  const float* dw     = (const float*)d_in[3];
  const float* sw     = (const float*)d_in[4];
  const float* ic     = (const float*)d_in[5];
  const float* bi     = (const float*)d_in[6];
  float* out = (float*)d_out;

  const int N  = in_sizes[0];   // 2^25
  const int nb = N / BPB;       // 2048 blocks

  float* coarse = (float*)d_ws;                 // 2048 floats
  float* fine   = coarse + 2048;                // 32768 floats
  u2*    pack   = (u2*)(fine + 32768);          // 16.8 MB

  k_pack_reduce<<<nb, BLOCK, 0, stream>>>(ann, bd, dw, sw, ic, bi,
                                          pack, coarse, fine);
  k_scan_out<<<nb, BLOCK, 0, stream>>>(pack, coarse, fine, origin,
                                       bd, dw, sw, ic, bi, out, nb);
}